// Round 6
// baseline (55.317 us; speedup 1.0000x reference)
//
#include <hip/hip_runtime.h>

// Degree-4 SH encoding: 12 B in, 64 B out per point. Write-bound streaming.
// R1: per-thread 256B blocks -> 2.4x write amplification (WRITE 650MB). Fixed R2.
// R2: LDS transpose, 1KB/wave lane-contiguous stores -> 67.7us (4.3 TB/s).
// R3: barrier-free direct (4 lanes/point, store idx tile*64+lane) -> 69.3us.
// R5: NONTEMPORAL stores -> 55.2us (5.3 TB/s). L3 write-allocate was the
//     limiter (268MB stream ~ 256MB Infinity Cache); theory confirmed.
// R6: 4-tile unroll -- 4 independent 1KB nt stores in flight per wave per
//     iteration (store-completion latency is full-HBM once L3 is bypassed;
//     raise per-wave MLP). If neutral: empirical mixed-stream roofline.

typedef float f32x4 __attribute__((ext_vector_type(4)));

__device__ __forceinline__ f32x4 sh_group(int c, float x, float y, float z) {
    const float xx = x * x, yy = y * y, zz = z * z;
    const float xy = x * y, yz = y * z, xz = x * z;
    f32x4 o;
    switch (c) {
    case 0:
        o.x = 0.28209479177387814f;
        o.y = -0.4886025119029199f * y;
        o.z =  0.4886025119029199f * z;
        o.w = -0.4886025119029199f * x;
        break;
    case 1:
        o.x =  1.0925484305920792f  * xy;
        o.y = -1.0925484305920792f  * yz;
        o.z =  0.31539156525252005f * (2.0f * zz - xx - yy);
        o.w = -1.0925484305920792f  * xz;
        break;
    case 2:
        o.x =  0.5462742152960396f  * (xx - yy);
        o.y = -0.5900435899266435f  * y * (3.0f * xx - yy);
        o.z =  2.890611442640554f   * xy * z;
        o.w = -0.4570457994644658f  * y * (4.0f * zz - xx - yy);
        break;
    default:
        o.x =  0.3731763325901154f  * z * (2.0f * zz - 3.0f * xx - 3.0f * yy);
        o.y = -0.4570457994644658f  * x * (4.0f * zz - xx - yy);
        o.z =  1.445305721320277f   * z * (xx - yy);
        o.w = -0.5900435899266435f  * x * (xx - 3.0f * yy);
        break;
    }
    return o;
}

__global__ __launch_bounds__(256)
void SHEncoder_53077205844617_kernel(const float* __restrict__ in,
                                     float* __restrict__ out,
                                     const int* __restrict__ size_ptr,
                                     int B) {
    const int lane = threadIdx.x & 63;
    const int wid  = blockIdx.x * (blockDim.x >> 6) + (threadIdx.x >> 6);
    const int nw   = gridDim.x * (blockDim.x >> 6);

    const float inv = 1.0f / (float)(*size_ptr);
    f32x4* __restrict__ out4 = (f32x4*)out;

    const int sub = lane >> 2;          // point within wave tile (0..15)
    const int c   = lane & 3;           // float4 group of that point
    const int ntiles = (B + 15) >> 4;   // 16 points per wave tile
    const int qlim   = 4 * B;

    for (int t0 = wid; t0 < ntiles; t0 += 4 * nw) {
        int   tt[4];
        float xv[4], yv[4], zv[4];

        // Issue all loads up front: 4 independent chains.
#pragma unroll
        for (int k = 0; k < 4; ++k) {
            const int t = t0 + k * nw;
            tt[k] = t;
            xv[k] = 0.f; yv[k] = 0.f; zv[k] = 0.f;
            if (t < ntiles) {
                const int p = t * 16 + sub;
                if (p < B) {
                    xv[k] = in[3 * p + 0];
                    yv[k] = in[3 * p + 1];
                    zv[k] = in[3 * p + 2];
                }
            }
        }

        // Compute + 4 independent 1KB-per-wave nt stores.
#pragma unroll
        for (int k = 0; k < 4; ++k) {
            if (tt[k] < ntiles) {
                const f32x4 o = sh_group(c, xv[k] * inv, yv[k] * inv, zv[k] * inv);
                const int qg = tt[k] * 64 + lane;    // == 4*p + c
                if (qg < qlim) __builtin_nontemporal_store(o, &out4[qg]);
            }
        }
    }
}

extern "C" void kernel_launch(void* const* d_in, const int* in_sizes, int n_in,
                              void* d_out, int out_size, void* d_ws, size_t ws_size,
                              hipStream_t stream) {
    const float* in       = (const float*)d_in[0];
    const int*   size_ptr = (const int*)d_in[1];
    float*       out      = (float*)d_out;

    const int B = in_sizes[0] / 3;

    const int threads = 256;
    const int ntiles  = (B + 15) >> 4;
    int blocks = (ntiles + 3) / 4;       // 4 waves/block
    if (blocks > 2048) blocks = 2048;
    if (blocks < 1) blocks = 1;

    SHEncoder_53077205844617_kernel<<<blocks, threads, 0, stream>>>(in, out, size_ptr, B);
}